// Round 1
// 2462.659 us; speedup vs baseline: 1.0126x; 1.0126x over previous
//
#include <hip/hip_runtime.h>

// DBRX MoE experts: B=4,S=2048,F=2048,H=4096,E=8,K=2. T = 8192 tokens.
// Sparse-routed bf16 MFMA implementation (only top-2 experts per token run:
// 0.825 TFLOP vs the reference's dense 3.3 TFLOP).
//
// R1: gemm1/gemm2 staging switched from reg-staged ds_write to
// __builtin_amdgcn_global_load_lds width=16 (m97 pattern), plus a both-sides
// 16B-chunk XOR swizzle (source-swizzled global addr + swizzled ds_read,
// rule #21) to kill the 8-way LDS bank conflict on fragment reads.

#define T_TOK 8192
#define FDIM  2048
#define HDIM  4096
#define NEXP  8
#define PAIR_CAP (T_TOK * 2)

typedef __bf16 bf16;
typedef __bf16 bf16x8 __attribute__((ext_vector_type(8)));
typedef __bf16 bf16x4 __attribute__((ext_vector_type(4)));
typedef float  f32x4  __attribute__((ext_vector_type(4)));

// async global->LDS, 16 bytes per lane. LDS dest must be wave-uniform base +
// lane*16 (our staging layout is exactly lds_byte = tid*16, linear).
__device__ __forceinline__ void gld16(const bf16* g, bf16* l) {
    __builtin_amdgcn_global_load_lds(
        (const __attribute__((address_space(1))) void*)g,
        (__attribute__((address_space(3))) void*)l, 16, 0, 0);
}

// ---------------- conversion kernels ----------------

// elementwise fp32 -> bf16, n4 = n/4 float4 groups
__global__ void cvt_kernel(const float* __restrict__ in, bf16* __restrict__ out, long n4) {
    long i = (long)blockIdx.x * blockDim.x + threadIdx.x;
    long stride = (long)gridDim.x * blockDim.x;
    for (; i < n4; i += stride) {
        float4 v = ((const float4*)in)[i];
        bf16x4 o;
        o[0] = (bf16)v.x; o[1] = (bf16)v.y; o[2] = (bf16)v.z; o[3] = (bf16)v.w;
        ((bf16x4*)out)[i] = o;
    }
}

// per-matrix [FDIM][HDIM] fp32 -> [HDIM][FDIM] bf16 (transpose + convert)
__global__ __launch_bounds__(256)
void transpose_cvt_kernel(const float* __restrict__ in, bf16* __restrict__ out) {
    const size_t msz = (size_t)FDIM * HDIM;
    const float* I = in + msz * blockIdx.z;
    bf16* O = out + msz * blockIdx.z;
    int h0 = blockIdx.x * 32, f0 = blockIdx.y * 32;
    __shared__ float t[32][33];
    int tx = threadIdx.x & 31, ty = threadIdx.x >> 5;  // ty: 0..7
#pragma unroll
    for (int i = 0; i < 4; i++)
        t[ty + 8 * i][tx] = I[(size_t)(f0 + ty + 8 * i) * HDIM + h0 + tx];
    __syncthreads();
#pragma unroll
    for (int i = 0; i < 4; i++)
        O[(size_t)(h0 + ty + 8 * i) * FDIM + f0 + tx] = (bf16)t[tx][ty + 8 * i];
}

// ---------------- routing ----------------

__global__ void route_count_kernel(const int* __restrict__ idx, int* __restrict__ cnt) {
    int t = blockIdx.x * blockDim.x + threadIdx.x;
    if (t >= T_TOK) return;
    int i0 = idx[2 * t], i1 = idx[2 * t + 1];
    atomicAdd(&cnt[i0], 1);
    if (i1 != i0) atomicAdd(&cnt[i1], 1);
}

__global__ void scan_kernel(const int* __restrict__ cnt, int* __restrict__ off) {
    if (threadIdx.x == 0) {
        int s = 0;
        for (int e = 0; e < NEXP; e++) { off[e] = s; s += cnt[e]; }
        off[NEXP] = s;
    }
}

__global__ void route_scatter_kernel(const int* __restrict__ idx, const float* __restrict__ wts,
                                     const int* __restrict__ off, int* __restrict__ fill,
                                     int* __restrict__ ptok, float* __restrict__ pwgt) {
    int t = blockIdx.x * blockDim.x + threadIdx.x;
    if (t >= T_TOK) return;
    int i0 = idx[2 * t], i1 = idx[2 * t + 1];
    float w0 = wts[2 * t], w1 = wts[2 * t + 1];
    if (i1 == i0) w0 += w1;  // merge duplicate expert picks (matches .at[].add)
    int p = off[i0] + atomicAdd(&fill[i0], 1);
    ptok[p] = t; pwgt[p] = w0;
    if (i1 != i0) {
        int q = off[i1] + atomicAdd(&fill[i1], 1);
        ptok[q] = t; pwgt[q] = w1;
    }
}

// ---------------- GEMM1: h = silu(x*w1) * (x*v1), gathered rows ----------------
// xb:[T_TOK][FDIM] bf16; w1t/v1t:[nz][HDIM][FDIM] bf16 (pre-transposed);
// hbuf rows indexed (serial? local : global pair pos)
//
// LDS tiles [128][32] bf16 (row stride 64B = 4x16B chunks). Staged via
// global_load_lds with linear dest (byte = tid*16). Bank-conflict fix:
// logical chunk c of row r lives at LDS slot c ^ ((r>>1)&3); we load the
// swizzled SOURCE chunk (involution) and ds_read at the swizzled slot.

__global__ __launch_bounds__(256)
void gemm1_kernel(const bf16* __restrict__ xb, const bf16* __restrict__ w1t,
                  const bf16* __restrict__ v1t, bf16* __restrict__ hbuf,
                  const int* __restrict__ ptok, const int* __restrict__ off,
                  int e0, int serial) {
    int e = e0 + blockIdx.z;
    int base = off[e], cnt = off[e + 1] - base;
    int m0 = blockIdx.y * 128;
    if (m0 >= cnt) return;
    int n0 = blockIdx.x * 128;
    size_t wstride = serial ? 0 : (size_t)HDIM * FDIM;
    const bf16* W1 = w1t + wstride * blockIdx.z;
    const bf16* V1 = v1t + wstride * blockIdx.z;
    int hrow0 = serial ? 0 : base;

    __shared__ __align__(16) bf16 As[128][32];
    __shared__ __align__(16) bf16 B1s[128][32];
    __shared__ __align__(16) bf16 B2s[128][32];

    int tid = threadIdx.x;
    int lane = tid & 63, wv = tid >> 6;
    int wm = (wv >> 1) * 64, wn = (wv & 1) * 64;
    int l15 = lane & 15, q = lane >> 4;        // q: 16B chunk idx (k-quad)

    // staging geometry: thread stages rows r0 and r0+64, one 16B chunk each
    int r0 = tid >> 2, c = tid & 3;
    int c_src = c ^ ((r0 >> 1) & 3);           // source-side swizzle (involution)

    int rr0 = m0 + r0;      if (rr0 >= cnt) rr0 = cnt - 1;
    int rr1 = m0 + r0 + 64; if (rr1 >= cnt) rr1 = cnt - 1;
    const bf16* gA0  = xb + (size_t)ptok[base + rr0] * FDIM + c_src * 8;
    const bf16* gA1  = xb + (size_t)ptok[base + rr1] * FDIM + c_src * 8;
    const bf16* gB10 = W1 + (size_t)(n0 + r0) * FDIM + c_src * 8;
    const bf16* gB11 = W1 + (size_t)(n0 + r0 + 64) * FDIM + c_src * 8;
    const bf16* gB20 = V1 + (size_t)(n0 + r0) * FDIM + c_src * 8;
    const bf16* gB21 = V1 + (size_t)(n0 + r0 + 64) * FDIM + c_src * 8;

    bf16* lA  = &As[0][0]  + tid * 8;   // byte offset tid*16, linear in lane order
    bf16* lB1 = &B1s[0][0] + tid * 8;
    bf16* lB2 = &B2s[0][0] + tid * 8;

    f32x4 acc1[4][4], acc2[4][4];
#pragma unroll
    for (int i = 0; i < 4; i++)
#pragma unroll
        for (int j = 0; j < 4; j++) {
            acc1[i][j] = (f32x4){0.f, 0.f, 0.f, 0.f};
            acc2[i][j] = (f32x4){0.f, 0.f, 0.f, 0.f};
        }

    // read-side swizzle: rows wm/wn + i*16 + l15 -> ((row>>1)&3) == ((l15>>1)&3)
    // (wm, wn, i*16 are multiples of 16), so the swizzled chunk is lane-constant.
    int swc = (q ^ ((l15 >> 1) & 3)) * 8;      // bf16-element column offset

    for (int kt = 0; kt < FDIM / 32; ++kt) {
        int kk = kt * 32;
        __syncthreads();                       // all waves done reading prev tile
        gld16(gA0 + kk, lA);        gld16(gA1 + kk, lA + 2048);
        gld16(gB10 + kk, lB1);      gld16(gB11 + kk, lB1 + 2048);
        gld16(gB20 + kk, lB2);      gld16(gB21 + kk, lB2 + 2048);
        __syncthreads();                       // vmcnt(0) drained -> LDS ready
        bf16x8 af[4], b1f[4], b2f[4];
#pragma unroll
        for (int i = 0; i < 4; i++) {
            af[i]  = *(const bf16x8*)(&As[0][0]  + (wm + i * 16 + l15) * 32 + swc);
            b1f[i] = *(const bf16x8*)(&B1s[0][0] + (wn + i * 16 + l15) * 32 + swc);
            b2f[i] = *(const bf16x8*)(&B2s[0][0] + (wn + i * 16 + l15) * 32 + swc);
        }
#pragma unroll
        for (int i = 0; i < 4; i++)
#pragma unroll
            for (int j = 0; j < 4; j++) {
                acc1[i][j] = __builtin_amdgcn_mfma_f32_16x16x32_bf16(af[i], b1f[j], acc1[i][j], 0, 0, 0);
                acc2[i][j] = __builtin_amdgcn_mfma_f32_16x16x32_bf16(af[i], b2f[j], acc2[i][j], 0, 0, 0);
            }
    }

    int rbase = (lane >> 4) * 4;
#pragma unroll
    for (int i = 0; i < 4; i++)
#pragma unroll
        for (int j = 0; j < 4; j++)
#pragma unroll
            for (int r = 0; r < 4; r++) {
                int gm = m0 + wm + i * 16 + rbase + r;
                if (gm < cnt) {
                    float g = acc1[i][j][r], u = acc2[i][j][r];
                    float s = g / (1.0f + __expf(-g));
                    hbuf[(size_t)(hrow0 + gm) * HDIM + n0 + wn + j * 16 + l15] = (bf16)(s * u);
                }
            }
}

// ---------------- GEMM2: out[token] += w * (h @ w2^T) ----------------
// hbuf:[rows][HDIM] bf16; w2b:[nz][FDIM][HDIM] bf16 (k-contiguous)

__global__ __launch_bounds__(256)
void gemm2_kernel(const bf16* __restrict__ hbuf, const bf16* __restrict__ w2b,
                  float* __restrict__ out, const int* __restrict__ ptok,
                  const float* __restrict__ pwgt, const int* __restrict__ off,
                  int e0, int serial) {
    int e = e0 + blockIdx.z;
    int base = off[e], cnt = off[e + 1] - base;
    int m0 = blockIdx.y * 128;
    if (m0 >= cnt) return;
    int n0 = blockIdx.x * 128;
    size_t wstride = serial ? 0 : (size_t)FDIM * HDIM;
    const bf16* W2 = w2b + wstride * blockIdx.z;
    int hrow0 = serial ? 0 : base;

    __shared__ __align__(16) bf16 As[128][32];
    __shared__ __align__(16) bf16 Bs[128][32];

    int tid = threadIdx.x;
    int lane = tid & 63, wv = tid >> 6;
    int wm = (wv >> 1) * 64, wn = (wv & 1) * 64;
    int l15 = lane & 15, q = lane >> 4;

    int r0 = tid >> 2, c = tid & 3;
    int c_src = c ^ ((r0 >> 1) & 3);

    int ra0 = m0 + r0;      if (ra0 >= cnt) ra0 = cnt - 1;
    int ra1 = m0 + r0 + 64; if (ra1 >= cnt) ra1 = cnt - 1;
    const bf16* gA0 = hbuf + (size_t)(hrow0 + ra0) * HDIM + c_src * 8;
    const bf16* gA1 = hbuf + (size_t)(hrow0 + ra1) * HDIM + c_src * 8;
    const bf16* gB0 = W2 + (size_t)(n0 + r0) * HDIM + c_src * 8;
    const bf16* gB1 = W2 + (size_t)(n0 + r0 + 64) * HDIM + c_src * 8;

    bf16* lA = &As[0][0] + tid * 8;
    bf16* lB = &Bs[0][0] + tid * 8;

    f32x4 acc[4][4];
#pragma unroll
    for (int i = 0; i < 4; i++)
#pragma unroll
        for (int j = 0; j < 4; j++) acc[i][j] = (f32x4){0.f, 0.f, 0.f, 0.f};

    int swc = (q ^ ((l15 >> 1) & 3)) * 8;

    for (int kt = 0; kt < HDIM / 32; ++kt) {
        int kk = kt * 32;
        __syncthreads();
        gld16(gA0 + kk, lA);    gld16(gA1 + kk, lA + 2048);
        gld16(gB0 + kk, lB);    gld16(gB1 + kk, lB + 2048);
        __syncthreads();
        bf16x8 af[4], bf[4];
#pragma unroll
        for (int i = 0; i < 4; i++) {
            af[i] = *(const bf16x8*)(&As[0][0] + (wm + i * 16 + l15) * 32 + swc);
            bf[i] = *(const bf16x8*)(&Bs[0][0] + (wn + i * 16 + l15) * 32 + swc);
        }
#pragma unroll
        for (int i = 0; i < 4; i++)
#pragma unroll
            for (int j = 0; j < 4; j++)
                acc[i][j] = __builtin_amdgcn_mfma_f32_16x16x32_bf16(af[i], bf[j], acc[i][j], 0, 0, 0);
    }

    int rbase = (lane >> 4) * 4;
#pragma unroll
    for (int i = 0; i < 4; i++)
#pragma unroll
        for (int r = 0; r < 4; r++) {
            int gm = m0 + wm + i * 16 + rbase + r;
            if (gm < cnt) {
                int pos = base + gm;
                int token = ptok[pos];
                float w = pwgt[pos];
#pragma unroll
                for (int j = 0; j < 4; j++) {
                    float v = acc[i][j][r] * w;
                    unsafeAtomicAdd(out + (size_t)token * FDIM + n0 + wn + j * 16 + l15, v);
                }
            }
        }
}

// ---------------- launch ----------------

extern "C" void kernel_launch(void* const* d_in, const int* in_sizes, int n_in,
                              void* d_out, int out_size, void* d_ws, size_t ws_size,
                              hipStream_t stream) {
    const float* x   = (const float*)d_in[0];
    const float* tkw = (const float*)d_in[1];
    const float* w1  = (const float*)d_in[2];
    const float* v1  = (const float*)d_in[3];
    const float* w2  = (const float*)d_in[4];
    const int*   tki = (const int*)d_in[5];
    float* out = (float*)d_out;

    char* W = (char*)d_ws;
    size_t cur = 0;
    auto take = [&](size_t b) -> char* {
        char* p = W + cur;
        cur += (b + 255) & ~(size_t)255;
        return p;
    };

    const size_t wmat = (size_t)FDIM * HDIM * 2;  // one expert matrix, bf16 bytes

    // Fixed-size region: ctrl + pair lists + xb
    const size_t fixed = 256 + ((sizeof(int) * PAIR_CAP + 255) & ~(size_t)255)
                             + ((sizeof(float) * PAIR_CAP + 255) & ~(size_t)255)
                             + ((size_t)T_TOK * FDIM * 2 + 255) & ~(size_t)255;
    const size_t need_batched = fixed + (size_t)PAIR_CAP * HDIM * 2 + 3 * (size_t)NEXP * wmat + 4096;
    const size_t need_serial  = fixed + (size_t)T_TOK * HDIM * 2 + 3 * wmat + 4096;

    // Workspace too small even for the serial tier: safe no-op (clean
    // validation failure instead of an OOB GPU fault that kills the container).
    if (ws_size < need_serial) return;
    bool batched = (ws_size >= need_batched);

    char* ctrl = take(256);
    int* cnt  = (int*)ctrl;
    int* fill = (int*)(ctrl + 64);
    int* off  = (int*)(ctrl + 128);
    int*   ptok = (int*)take(sizeof(int) * PAIR_CAP);
    float* pwgt = (float*)take(sizeof(float) * PAIR_CAP);
    bf16* xb = (bf16*)take((size_t)T_TOK * FDIM * 2);

    bf16* hbuf = (bf16*)take((size_t)(batched ? PAIR_CAP : T_TOK) * HDIM * 2);
    bf16* w1t = (bf16*)take((batched ? NEXP : 1) * wmat);
    bf16* v1t = (bf16*)take((batched ? NEXP : 1) * wmat);
    bf16* w2b = (bf16*)take((batched ? NEXP : 1) * wmat);

    hipMemsetAsync(ctrl, 0, 128, stream);
    hipMemsetAsync(d_out, 0, (size_t)out_size * sizeof(float), stream);

    cvt_kernel<<<2048, 256, 0, stream>>>(x, xb, (long)T_TOK * FDIM / 4);
    route_count_kernel<<<T_TOK / 256, 256, 0, stream>>>(tki, cnt);
    scan_kernel<<<1, 64, 0, stream>>>(cnt, off);
    route_scatter_kernel<<<T_TOK / 256, 256, 0, stream>>>(tki, tkw, off, fill, ptok, pwgt);

    if (batched) {
        transpose_cvt_kernel<<<dim3(HDIM / 32, FDIM / 32, NEXP), 256, 0, stream>>>(w1, w1t);
        transpose_cvt_kernel<<<dim3(HDIM / 32, FDIM / 32, NEXP), 256, 0, stream>>>(v1, v1t);
        cvt_kernel<<<8192, 256, 0, stream>>>(w2, w2b, (long)NEXP * FDIM * HDIM / 4);
        gemm1_kernel<<<dim3(HDIM / 128, T_TOK / 128, NEXP), 256, 0, stream>>>(
            xb, w1t, v1t, hbuf, ptok, off, 0, 0);
        gemm2_kernel<<<dim3(FDIM / 128, T_TOK / 128, NEXP), 256, 0, stream>>>(
            hbuf, w2b, out, ptok, pwgt, off, 0, 0);
    } else {
        for (int e = 0; e < NEXP; e++) {
            const size_t moff = (size_t)e * FDIM * HDIM;
            transpose_cvt_kernel<<<dim3(HDIM / 32, FDIM / 32, 1), 256, 0, stream>>>(w1 + moff, w1t);
            transpose_cvt_kernel<<<dim3(HDIM / 32, FDIM / 32, 1), 256, 0, stream>>>(v1 + moff, v1t);
            cvt_kernel<<<2048, 256, 0, stream>>>(w2 + moff, w2b, (long)FDIM * HDIM / 4);
            gemm1_kernel<<<dim3(HDIM / 128, T_TOK / 128, 1), 256, 0, stream>>>(
                xb, w1t, v1t, hbuf, ptok, off, e, 1);
            gemm2_kernel<<<dim3(FDIM / 128, T_TOK / 128, 1), 256, 0, stream>>>(
                hbuf, w2b, out, ptok, pwgt, off, e, 1);
        }
    }
}